// Round 2
// baseline (160.841 us; speedup 1.0000x reference)
//
#include <hip/hip_runtime.h>
#include <hip/hip_bf16.h>
#include <stdint.h>

// B=8, N=1024, D=512, H=8, DK=64, ALPHA=0.2
//
// Scratch plan (robust to small ws_size):
//   ws  : xb (attention output, bf16 [8192][512]) @ 0, 8,388,608 bytes.
//         (only intermediate alive while the final GEMM writes d_out)
//   d_out (16,777,216 bytes f32) doubles as scratch; all regions are
//   write-before-read within one call and dead before gemm<0> overwrites:
//     vt   @ 0          8,388,608  (v^T per head: [b][h][dk][n] bf16)
//     mbit @ 8,388,608  1,048,576  (mask bitset, [b][i][128B])
//     sq   @ 9,437,184    262,144  ([b][h][n] f32)
//     sk   @ 9,699,328    262,144
//     Aq   @ 9,961,472     16,384  ([d][h] f32)
//     Ak   @ 9,977,856     16,384
//     qb   @ 9,994,240        256
//     kb   @ 9,994,496        256   (end 9,994,752 < 16,777,216)

typedef __attribute__((ext_vector_type(8))) short short8;
typedef __attribute__((ext_vector_type(4))) float f32x4;

#define LB __launch_bounds__(256)

__device__ __forceinline__ unsigned short f2bf(float f) {
  unsigned int u = __float_as_uint(f);
  u += 0x7fffu + ((u >> 16) & 1u);
  return (unsigned short)(u >> 16);
}

// ---------------- fold attention vector a into Wq/Wk ----------------
// Aq[d][h] = sum_dk Wq[h*64+dk][d] * a[h][dk];  qb[h] = bq[h*64:]·a[h][:64]
__global__ LB void prep_a_kernel(const float* __restrict__ Wq, const float* __restrict__ Wk,
                                 const float* __restrict__ a, const float* __restrict__ bq,
                                 const float* __restrict__ bk,
                                 float* __restrict__ Aq, float* __restrict__ Ak,
                                 float* __restrict__ qb, float* __restrict__ kb) {
  const int t = blockIdx.x * 256 + threadIdx.x;  // 4096 threads: (d,h)
  const int h = t & 7, d = t >> 3;
  float aq = 0.f, ak = 0.f;
  for (int dk = 0; dk < 64; ++dk) {
    aq += Wq[(size_t)(h * 64 + dk) * 512 + d] * a[h * 128 + dk];
    ak += Wk[(size_t)(h * 64 + dk) * 512 + d] * a[h * 128 + 64 + dk];
  }
  Aq[d * 8 + h] = aq;
  Ak[d * 8 + h] = ak;
  if (d == 0) {
    float s1 = 0.f, s2 = 0.f;
    for (int dk = 0; dk < 64; ++dk) {
      s1 += bq[h * 64 + dk] * a[h * 128 + dk];
      s2 += bk[h * 64 + dk] * a[h * 128 + 64 + dk];
    }
    qb[h] = s1;
    kb[h] = s2;
  }
}

// ---------------- sq/sk: rank-8 projections of query/key ----------------
__global__ LB void sqsk_kernel(const float* __restrict__ query, const float* __restrict__ key,
                               const float* __restrict__ Aq, const float* __restrict__ Ak,
                               const float* __restrict__ qb, const float* __restrict__ kb,
                               float* __restrict__ sq, float* __restrict__ sk) {
  const int t = blockIdx.x * 256 + threadIdx.x;  // 65536 threads: (row, h)
  const int h = t & 7, r = t >> 3;
  const float* qrow = query + (size_t)r * 512;
  const float* krow = key + (size_t)r * 512;
  float aq = 0.f, ak = 0.f;
  for (int d = 0; d < 512; d += 4) {
    const float4 qv = *(const float4*)(qrow + d);
    const float4 kv = *(const float4*)(krow + d);
    aq += qv.x * Aq[(d + 0) * 8 + h] + qv.y * Aq[(d + 1) * 8 + h]
        + qv.z * Aq[(d + 2) * 8 + h] + qv.w * Aq[(d + 3) * 8 + h];
    ak += kv.x * Ak[(d + 0) * 8 + h] + kv.y * Ak[(d + 1) * 8 + h]
        + kv.z * Ak[(d + 2) * 8 + h] + kv.w * Ak[(d + 3) * 8 + h];
  }
  const int b = r >> 10, n = r & 1023;
  sq[((size_t)b * 8 + h) * 1024 + n] = aq + qb[h];
  sk[((size_t)b * 8 + h) * 1024 + n] = ak + kb[h];
}

// ---------------- mask (B,N,N) int32 -> bitset ----------------
__global__ LB void maskbits_kernel(const int* __restrict__ mask,
                                   unsigned int* __restrict__ bits) {
  const size_t idx = (size_t)blockIdx.x * 256 + threadIdx.x;
  const unsigned long long bl = __ballot(mask[idx] != 0);
  if ((threadIdx.x & 63) == 0) {
    bits[idx >> 5] = (unsigned int)bl;
    bits[(idx >> 5) + 1] = (unsigned int)(bl >> 32);
  }
}

// ---------------- bf16 MFMA GEMM: C[8192|M][512] = A @ Bw[512][512]^T + bias
// AF32: A is fp32 (cast to bf16 during staging); else A is bf16.
// B (weights) always fp32, cast during staging.
// MODE 0: C -> fp32 row-major.  MODE 1: C -> bf16 v^T layout [b][h][dk][n].
template <int AF32, int MODE>
__global__ LB void gemm_bt(const void* __restrict__ Ap,
                           const float* __restrict__ Bw,
                           const float* __restrict__ bias, void* __restrict__ outp) {
  __shared__ unsigned short As[128 * 32];
  __shared__ unsigned short Bs[128 * 32];
  const int tid = threadIdx.x;
  const int w = tid >> 6, l = tid & 63;
  const int lr = l & 15, lc = l >> 4;
  const int bm = blockIdx.x >> 2, bn = blockIdx.x & 3;  // grid 256: 64 x 4
  const int m0 = bm * 128, n0 = bn * 128;
  const int wr = (w >> 1) * 64, wc = (w & 1) * 64;
  f32x4 acc[4][4] = {};
  for (int kt = 0; kt < 16; ++kt) {
    const int k0 = kt * 32;
    if (kt) __syncthreads();
#pragma unroll
    for (int it = 0; it < 2; ++it) {
      int idx = it * 256 + tid;  // 0..511
      int row = idx >> 2, gr = idx & 3;
      // A panel
      if (AF32) {
        const float4* src = (const float4*)((const float*)Ap + (size_t)(m0 + row) * 512 + k0 + gr * 8);
        const float4 a0 = src[0], a1 = src[1];
        unsigned short t8[8] = {f2bf(a0.x), f2bf(a0.y), f2bf(a0.z), f2bf(a0.w),
                                f2bf(a1.x), f2bf(a1.y), f2bf(a1.z), f2bf(a1.w)};
        *(short8*)(As + row * 32 + gr * 8) = *(short8*)t8;
      } else {
        *(short8*)(As + row * 32 + gr * 8) =
            *(const short8*)((const unsigned short*)Ap + (size_t)(m0 + row) * 512 + k0 + gr * 8);
      }
      // B panel (always f32 weights)
      {
        const float4* src = (const float4*)(Bw + (size_t)(n0 + row) * 512 + k0 + gr * 8);
        const float4 b0 = src[0], b1 = src[1];
        unsigned short t8[8] = {f2bf(b0.x), f2bf(b0.y), f2bf(b0.z), f2bf(b0.w),
                                f2bf(b1.x), f2bf(b1.y), f2bf(b1.z), f2bf(b1.w)};
        *(short8*)(Bs + row * 32 + gr * 8) = *(short8*)t8;
      }
    }
    __syncthreads();
    short8 af[4], bfr[4];
#pragma unroll
    for (int g = 0; g < 4; ++g) {
      af[g]  = *(const short8*)(As + (wr + g * 16 + lr) * 32 + lc * 8);
      bfr[g] = *(const short8*)(Bs + (wc + g * 16 + lr) * 32 + lc * 8);
    }
#pragma unroll
    for (int i = 0; i < 4; ++i)
#pragma unroll
      for (int j = 0; j < 4; ++j)
        acc[i][j] = __builtin_amdgcn_mfma_f32_16x16x32_bf16(af[i], bfr[j], acc[i][j], 0, 0, 0);
  }
#pragma unroll
  for (int i = 0; i < 4; ++i) {
#pragma unroll
    for (int j = 0; j < 4; ++j) {
      const int nn = n0 + wc + j * 16 + lr;
      const float bia = bias[nn];
      if (MODE == 0) {
        float* out = (float*)outp;
#pragma unroll
        for (int r = 0; r < 4; ++r) {
          const int mm = m0 + wr + i * 16 + lc * 4 + r;
          out[(size_t)mm * 512 + nn] = acc[i][j][r] + bia;
        }
      } else {
        unsigned short* out = (unsigned short*)outp;
        const int mm0 = m0 + wr + i * 16 + lc * 4;
        const int b = mm0 >> 10, t0 = mm0 & 1023;
        const int h = nn >> 6, dk = nn & 63;
        unsigned long long pk = 0;
#pragma unroll
        for (int r = 0; r < 4; ++r)
          pk |= (unsigned long long)f2bf(acc[i][j][r] + bia) << (16 * r);
        *(unsigned long long*)(out + (((size_t)((b * 8 + h) * 64 + dk)) << 10) + t0) = pk;
      }
    }
  }
}

// ---------------- fused attention: w=exp(lrelu(sq_i+sk_j))*mask; x = (w @ v)/rowsum
// wave = 32 i-rows x one head; rowsum via all-ones MFMA B operand (lands in D layout).
__global__ LB void attn_kernel(const float* __restrict__ sq, const float* __restrict__ sk,
                               const unsigned char* __restrict__ mbits,
                               const unsigned short* __restrict__ vt,
                               unsigned short* __restrict__ xb) {
  const int tid = threadIdx.x;
  const int w = tid >> 6, l = tid & 63;
  const int lr = l & 15, lc = l >> 4;
  const int bid = blockIdx.x;  // 512 blocks: b(8) x h(8) x iq(8)
  const int b = bid >> 6, r6 = bid & 63, h = r6 >> 3, iq = r6 & 7;
  const int i0 = iq * 128 + w * 32;
  const int bh = b * 8 + h;
  const float* sqp = sq + (size_t)bh * 1024;
  const float* skp = sk + (size_t)bh * 1024;
  const unsigned short* vtp = vt + ((size_t)bh << 16);
  const unsigned char* mrow = mbits + ((size_t)b << 17);
  float sq2[2];
#pragma unroll
  for (int g = 0; g < 2; ++g) sq2[g] = sqp[i0 + g * 16 + lr];
  f32x4 acc[2][4] = {};
  f32x4 accs[2] = {};
  short8 ones;
#pragma unroll
  for (int t = 0; t < 8; ++t) ones[t] = (short)0x3f80;  // bf16 1.0
  for (int jt = 0; jt < 32; ++jt) {
    const int jb = jt * 32;
    const float4* skv4 = (const float4*)(skp + jb + lc * 8);
    const float4 s0 = skv4[0], s1 = skv4[1];
    const float skl[8] = {s0.x, s0.y, s0.z, s0.w, s1.x, s1.y, s1.z, s1.w};
    short8 pa[2];
#pragma unroll
    for (int g = 0; g < 2; ++g) {
      const int i = i0 + g * 16 + lr;
      const unsigned int mb = mrow[((size_t)i << 7) + (jb >> 3) + lc];
      const float sqv = sq2[g];
#pragma unroll
      for (int t = 0; t < 8; ++t) {
        float s = sqv + skl[t];
        s = fmaxf(s, 0.2f * s);                       // leaky relu
        const float wv = ((mb >> t) & 1u) ? __expf(s) : 0.0f;
        pa[g][t] = (short)f2bf(wv);
      }
    }
#pragma unroll
    for (int c = 0; c < 4; ++c) {
      const short8 bv = *(const short8*)(vtp + (((size_t)(c * 16 + lr)) << 10) + jb + lc * 8);
#pragma unroll
      for (int g = 0; g < 2; ++g)
        acc[g][c] = __builtin_amdgcn_mfma_f32_16x16x32_bf16(pa[g], bv, acc[g][c], 0, 0, 0);
    }
#pragma unroll
    for (int g = 0; g < 2; ++g)
      accs[g] = __builtin_amdgcn_mfma_f32_16x16x32_bf16(pa[g], ones, accs[g], 0, 0, 0);
  }
#pragma unroll
  for (int g = 0; g < 2; ++g) {
#pragma unroll
    for (int r = 0; r < 4; ++r) {
      const float s = accs[g][r];
      const float inv = s > 0.0f ? 1.0f / s : 0.0f;  // fully-masked row -> 0
      const int i = i0 + g * 16 + lc * 4 + r;
#pragma unroll
      for (int c = 0; c < 4; ++c)
        xb[(((size_t)(b * 1024 + i)) << 9) + h * 64 + c * 16 + lr] =
            f2bf(acc[g][c][r] * inv);
    }
  }
}

extern "C" void kernel_launch(void* const* d_in, const int* in_sizes, int n_in,
                              void* d_out, int out_size, void* d_ws, size_t ws_size,
                              hipStream_t stream) {
  const float* query = (const float*)d_in[0];
  const float* key   = (const float*)d_in[1];
  const float* value = (const float*)d_in[2];
  const int*   mask  = (const int*)d_in[3];
  const float* Wq = (const float*)d_in[4];
  const float* bq = (const float*)d_in[5];
  const float* Wk = (const float*)d_in[6];
  const float* bk = (const float*)d_in[7];
  const float* Wv = (const float*)d_in[8];
  const float* bv = (const float*)d_in[9];
  const float* Wo = (const float*)d_in[10];
  const float* bo = (const float*)d_in[11];
  const float* a  = (const float*)d_in[12];

  // d_out doubles as scratch (fully overwritten by the final GEMM).
  char* oc = (char*)d_out;
  unsigned short* vt = (unsigned short*)(oc + 0);
  unsigned int* mbits = (unsigned int*)(oc + 8388608);
  float* sqv = (float*)(oc + 9437184);
  float* skv = (float*)(oc + 9699328);
  float* Aq  = (float*)(oc + 9961472);
  float* Ak  = (float*)(oc + 9977856);
  float* qbf = (float*)(oc + 9994240);
  float* kbf = (float*)(oc + 9994496);
  // ws: only the attention output (must not alias d_out during final GEMM).
  unsigned short* xb = (unsigned short*)d_ws;  // 8,388,608 bytes

  prep_a_kernel<<<16, 256, 0, stream>>>(Wq, Wk, a, bq, bk, Aq, Ak, qbf, kbf);
  sqsk_kernel<<<256, 256, 0, stream>>>(query, key, Aq, Ak, qbf, kbf, sqv, skv);
  maskbits_kernel<<<32768, 256, 0, stream>>>(mask, mbits);
  gemm_bt<1, 1><<<256, 256, 0, stream>>>((const void*)value, Wv, bv, (void*)vt);
  attn_kernel<<<512, 256, 0, stream>>>(sqv, skv, (const unsigned char*)mbits, vt, xb);
  gemm_bt<0, 0><<<256, 256, 0, stream>>>((const void*)xb, Wo, bo, d_out);
}